// Round 6
// baseline (87.328 us; speedup 1.0000x reference)
//
#include <hip/hip_runtime.h>
#include <math.h>

#define NB 4
#define NN 256
#define MAT (NN*NN)      // 65536
#define BMAT (NB*MAT)    // 262144
#define ALPHA 0.2f

typedef __attribute__((ext_vector_type(8))) __bf16 bf16x8;
typedef __attribute__((ext_vector_type(4))) float f32x4;

union U8 { bf16x8 v; unsigned short u[8]; };

__device__ __forceinline__ unsigned short f2bf(float x) {
    unsigned u = __float_as_uint(x);
    u = (u + 0x7FFFu + ((u >> 16) & 1u)) >> 16;
    return (unsigned short)u;
}
__device__ __forceinline__ float bf2f(unsigned short h) {
    return __uint_as_float(((unsigned)h) << 16);
}
__device__ __forceinline__ void split3(float x, unsigned short& a,
                                       unsigned short& b, unsigned short& c) {
    a = f2bf(x); float r = x - bf2f(a);
    b = f2bf(r); r -= bf2f(b);
    c = f2bf(r);
}

__device__ __forceinline__ float wave_sum(float v) {
#pragma unroll
    for (int o = 32; o > 0; o >>= 1) v += __shfl_down(v, o, 64);
    return v;
}
__device__ __forceinline__ float block_sum256(float v, volatile float* red) {
    int lane = threadIdx.x & 63, w = threadIdx.x >> 6;
    v = wave_sum(v);
    __syncthreads();
    if (lane == 0) red[w] = v;
    __syncthreads();
    return red[0] + red[1] + red[2] + red[3];
}

// ---- k_pre: 2048 blocks. bid<1024: W split+transpose (4 matrices).
//            bid>=1024: E split into 3 bf16 planes (layer-0 input).
__global__ __launch_bounds__(256) void k_pre(
    const float* __restrict__ w0, const float* __restrict__ w1,
    const float* __restrict__ w2, const float* __restrict__ w3,
    const float* __restrict__ edges,
    unsigned short* __restrict__ WT, unsigned short* __restrict__ Epl)
{
    int bid = blockIdx.x, tid = threadIdx.x;
    if (bid < 1024) {
        int m = bid >> 8, k = bid & 255, j = tid;
        const float* Wm = (m == 0) ? w0 : (m == 1) ? w1 : (m == 2) ? w2 : w3;
        float x = Wm[k * NN + j];
        unsigned short s0, s1, s2; split3(x, s0, s1, s2);
        unsigned short* base = WT + m * 3 * MAT;
        base[0 * MAT + j * NN + k] = s0;
        base[1 * MAT + j * NN + k] = s1;
        base[2 * MAT + j * NN + k] = s2;
    } else {
        int idx = (bid - 1024) * 256 + tid;
        unsigned short s0, s1, s2; split3(edges[idx], s0, s1, s2);
        Epl[idx] = s0; Epl[BMAT + idx] = s1; Epl[2 * BMAT + idx] = s2;
    }
}

// ---- k_gh: G = E@wa+ba (+ GT), H = E@wp+bp. 1024 one-wave blocks, 16x32 tiles.
__global__ __launch_bounds__(64) void k_gh(
    const unsigned short* __restrict__ Epl,
    const unsigned short* __restrict__ WTa, const float* __restrict__ ba,
    const unsigned short* __restrict__ WTp, const float* __restrict__ bp,
    float* __restrict__ G, float* __restrict__ GT, float* __restrict__ H)
{
    int bid = blockIdx.x;
    int m = bid >> 9, b = (bid >> 7) & 3, t = bid & 127;
    int tm = t >> 3, tn = t & 7;
    const unsigned short* WT = m ? WTp : WTa;
    const float* bias = m ? bp : ba;
    float* C = (m ? H : G) + b * MAT;
    int l = threadIdx.x, l15 = l & 15, lk = (l >> 4) * 8, lk4 = l >> 4;

    f32x4 acc[2]; acc[0] = 0.0f; acc[1] = 0.0f;
    int arow = b * MAT + (tm * 16 + l15) * NN;
    for (int k0 = 0; k0 < NN; k0 += 32) {
        int kb = k0 + lk;
        U8 a[3], w[3][2];
#pragma unroll
        for (int p = 0; p < 3; ++p)
            a[p].v = *(const bf16x8*)&Epl[p * BMAT + arow + kb];
#pragma unroll
        for (int cg = 0; cg < 2; ++cg) {
            int col = tn * 32 + cg * 16 + l15;
#pragma unroll
            for (int p = 0; p < 3; ++p)
                w[p][cg].v = *(const bf16x8*)&WT[p * MAT + col * NN + kb];
        }
        const int TP[6] = {0, 0, 1, 0, 1, 2}, TQ[6] = {0, 1, 0, 2, 1, 0};
#pragma unroll
        for (int t6 = 0; t6 < 6; ++t6)
#pragma unroll
            for (int cg = 0; cg < 2; ++cg)
                acc[cg] = __builtin_amdgcn_mfma_f32_16x16x32_bf16(
                    a[TP[t6]].v, w[TQ[t6]][cg].v, acc[cg], 0, 0, 0);
    }
#pragma unroll
    for (int cg = 0; cg < 2; ++cg) {
        int col = tn * 32 + cg * 16 + l15;
        float bv = bias[col];
#pragma unroll
        for (int r = 0; r < 4; ++r) {
            int row = tm * 16 + lk4 * 4 + r;
            C[row * NN + col] = acc[cg][r] + bv;
        }
        if (m == 0) {   // transposed store of G (+bias) into GT, 16B/lane
            f32x4 tv;
#pragma unroll
            for (int r = 0; r < 4; ++r) tv[r] = acc[cg][r] + bv;
            *(f32x4*)&GT[b * MAT + col * NN + tm * 16 + lk4 * 4] = tv;
        }
    }
}

// ---- k_fsym: per tile-pair (ti,tj): stage adj/eL/eH rows in LDS, MFMA D/N
// for both sides, divide+fallback, symmetrize; FINAL: tanh+dup store,
// else: 3-split next-layer E planes. grid (136, NB) x 256.
template<int FINAL>
__global__ __launch_bounds__(256) void k_fsym(
    const float* __restrict__ G, const float* __restrict__ GT,
    const float* __restrict__ Hm, const float* __restrict__ ae,
    unsigned short* __restrict__ Epl, float* __restrict__ out)
{
    __shared__ unsigned short adjL[32 * 256];
    __shared__ unsigned short eL0[32 * 256], eL1[32 * 256];
    __shared__ unsigned short eH0[32 * 256], eH1[32 * 256];
    __shared__ float DN[4][16 * 17];
    __shared__ float cntL[32], rsL[32];
    __shared__ float red[4];

    int b = blockIdx.y;
    int ti = 0, rem = blockIdx.x;
    while (rem >= 16 - ti) { rem -= 16 - ti; ++ti; }
    int tj = ti + rem;
    int t = threadIdx.x;

    float S = block_sum256(ae[t] + ae[t + 256], red);

    // ---- prep: local rows 0..15 = tile ti, 16..31 = tile tj; 8 thr/row
    int rl = t >> 3;
    int c0 = (t & 7) * 32;
    int grow = (rl < 16) ? (ti * 16 + rl) : (tj * 16 + rl - 16);
    int gbase = b * MAT + grow * NN + c0;
    int rowb = rl * 512;          // byte base of LDS row
    int sw = (rl & 7) << 4;       // XOR swizzle (16B granule)
    float hreg[32];
    float cntp = 0.f, hsum = 0.f, lmax = -3.4e38f;
#pragma unroll
    for (int c = 0; c < 32; c += 4) {
        f32x4 gq = *(const f32x4*)&G[gbase + c];
        f32x4 gt = *(const f32x4*)&GT[gbase + c];
        f32x4 hv = *(const f32x4*)&Hm[gbase + c];
#pragma unroll
        for (int i = 0; i < 4; ++i) {
            float av = (gq[i] + gt[i] > 0.f) ? 1.f : 0.f;
            cntp += av;
            int byte = rowb + (c0 + c + i) * 2;
            adjL[(byte ^ sw) >> 1] = f2bf(av);
            float h = hv[i];
            hreg[c + i] = h;
            hsum += h;
            float x = S * h;
            lmax = fmaxf(lmax, (x > 0.f) ? x : ALPHA * x);
        }
    }
#pragma unroll
    for (int o = 1; o < 8; o <<= 1) {     // reduce across the row's 8 lanes
        lmax = fmaxf(lmax, __shfl_xor(lmax, o, 64));
        hsum += __shfl_xor(hsum, o, 64);
        cntp += __shfl_xor(cntp, o, 64);
    }
    if ((t & 7) == 0) { cntL[rl] = cntp; rsL[rl] = hsum; }
#pragma unroll
    for (int c = 0; c < 32; ++c) {
        float h = hreg[c];
        float x = S * h;
        float L = (x > 0.f) ? x : ALPHA * x;
        float e = __expf(L - lmax);
        float eh = e * h;
        unsigned short p0 = f2bf(e);
        unsigned short p1 = f2bf(e - bf2f(p0));
        unsigned short q0 = f2bf(eh);
        unsigned short q1 = f2bf(eh - bf2f(q0));
        int byte = rowb + (c0 + c) * 2;
        int idx = (byte ^ sw) >> 1;
        eL0[idx] = p0; eL1[idx] = p1; eH0[idx] = q0; eH1[idx] = q1;
    }
    __syncthreads();

    // ---- MFMA: wave w: side=w>>1 (A: rows ti/cols tj; B: rows tj/cols ti),
    // which=w&1 (0: D from eL, 1: N from eH)
    {
        int w = t >> 6, lane = t & 63;
        int side = w >> 1, which = w & 1;
        int ar = (side ? 16 : 0) + (lane & 15);
        int br = (side ? 0 : 16) + (lane & 15);
        int lk = (lane >> 4) * 8;
        const unsigned short* P0 = which ? eH0 : eL0;
        const unsigned short* P1 = which ? eH1 : eL1;
        int asw = (ar & 7) << 4, bsw = (br & 7) << 4;
        f32x4 acc = 0.0f;
        for (int k0 = 0; k0 < NN; k0 += 32) {
            int kb2 = (k0 + lk) * 2;
            int ai = ((ar * 512 + kb2) ^ asw) >> 1;
            int bi = ((br * 512 + kb2) ^ bsw) >> 1;
            bf16x8 a0 = *(const bf16x8*)&P0[ai];
            bf16x8 a1 = *(const bf16x8*)&P1[ai];
            bf16x8 bv = *(const bf16x8*)&adjL[bi];
            acc = __builtin_amdgcn_mfma_f32_16x16x32_bf16(a0, bv, acc, 0, 0, 0);
            acc = __builtin_amdgcn_mfma_f32_16x16x32_bf16(a1, bv, acc, 0, 0, 0);
        }
#pragma unroll
        for (int r = 0; r < 4; ++r)
            DN[w][((lane >> 4) * 4 + r) * 17 + (lane & 15)] = acc[r];
    }
    __syncthreads();

    // ---- epilogue: F both sides, symmetrize, store
    int r = t >> 4, c = t & 15;
    float Fa = (cntL[16 + c] > 0.5f) ? DN[1][r * 17 + c] / DN[0][r * 17 + c]
                                     : rsL[r] * (1.f / 256.f);
    float Fb = (cntL[c] > 0.5f) ? DN[3][r * 17 + c] / DN[2][r * 17 + c]
                                : rsL[16 + r] * (1.f / 256.f);
    __syncthreads();
    float* FaS = DN[0];
    float* FbS = DN[1];
    FaS[r * 17 + c] = Fa;
    FbS[r * 17 + c] = Fb;
    __syncthreads();
    float ea = 0.5f * (Fa + FbS[c * 17 + r]);
    float eb = 0.5f * (Fb + FaS[c * 17 + r]);
    int idxA = b * MAT + (ti * 16 + r) * NN + tj * 16 + c;
    int idxB = b * MAT + (tj * 16 + r) * NN + ti * 16 + c;
    if (FINAL) {
        float ta = tanhf(ea), tb = tanhf(eb);
        out[idxA] = ta; out[BMAT + idxA] = ta;
        out[idxB] = tb; out[BMAT + idxB] = tb;   // ti==tj: same values, benign
    } else {
        unsigned short s0, s1, s2;
        split3(ea, s0, s1, s2);
        Epl[idxA] = s0; Epl[BMAT + idxA] = s1; Epl[2 * BMAT + idxA] = s2;
        split3(eb, s0, s1, s2);
        Epl[idxB] = s0; Epl[BMAT + idxB] = s1; Epl[2 * BMAT + idxB] = s2;
    }
}

extern "C" void kernel_launch(void* const* d_in, const int* in_sizes, int n_in,
                              void* d_out, int out_size, void* d_ws, size_t ws_size,
                              hipStream_t stream) {
    const float* edges = (const float*)d_in[1];
    const float* wp[2] = {(const float*)d_in[7],  (const float*)d_in[17]};
    const float* bp[2] = {(const float*)d_in[8],  (const float*)d_in[18]};
    const float* ae[2] = {(const float*)d_in[9],  (const float*)d_in[19]};
    const float* wa[2] = {(const float*)d_in[10], (const float*)d_in[20]};
    const float* ba[2] = {(const float*)d_in[11], (const float*)d_in[21]};
    float* out = (float*)d_out;

    // ws layout (~7.7 MB)
    unsigned short* WT   = (unsigned short*)d_ws;     // 12 planes * 128KB
    unsigned short* EplA = WT + 12 * MAT;             // 3 * BMAT bf16
    unsigned short* EplB = EplA + 3 * BMAT;           // 3 * BMAT bf16
    float* G  = (float*)(EplB + 3 * BMAT);            // 1MB
    float* GT = G + BMAT;                             // 1MB
    float* H  = GT + BMAT;                            // 1MB

    k_pre<<<2048, 256, 0, stream>>>(wa[0], wp[0], wa[1], wp[1], edges, WT, EplA);

    for (int l = 0; l < 2; ++l) {
        const unsigned short* WTa = WT + (l * 2 + 0) * 3 * MAT;
        const unsigned short* WTp = WT + (l * 2 + 1) * 3 * MAT;
        const unsigned short* Ein = l ? EplB : EplA;
        k_gh<<<1024, 64, 0, stream>>>(Ein, WTa, ba[l], WTp, bp[l], G, GT, H);
        if (l == 0)
            k_fsym<0><<<dim3(136, NB), 256, 0, stream>>>(G, GT, H, ae[l], EplB, nullptr);
        else
            k_fsym<1><<<dim3(136, NB), 256, 0, stream>>>(G, GT, H, ae[l], nullptr, out);
    }
}